// Round 11
// baseline (671.722 us; speedup 1.0000x reference)
//
#include <hip/hip_runtime.h>
#include <hip/hip_bf16.h>

using u16 = unsigned short;
using u32 = unsigned int;

typedef __bf16 bf16x8 __attribute__((ext_vector_type(8)));
typedef float  f32x4  __attribute__((ext_vector_type(4)));
typedef u32    u32x4  __attribute__((ext_vector_type(4)));
typedef u16    u16x8  __attribute__((ext_vector_type(8)));
typedef int    i32x4  __attribute__((ext_vector_type(4)));

__device__ __forceinline__ float bflo(u32 u){ union { u32 u; float f; } c; c.u = u << 16;          return c.f; }
__device__ __forceinline__ float bfhi(u32 u){ union { u32 u; float f; } c; c.u = u & 0xffff0000u;  return c.f; }
__device__ __forceinline__ u16  f2bf(float f){
  union { float f; u32 u; } c; c.f = f;
  u32 u = c.u;
  return (u16)((u + 0x7fffu + ((u >> 16) & 1u)) >> 16); // RNE
}

__device__ __forceinline__ void gload_lds16(const void* g, void* l){
  __builtin_amdgcn_global_load_lds(
      (const __attribute__((address_space(1))) void*)g,
      (__attribute__((address_space(3))) void*)l, 16, 0, 0);
}

// ---------------- fused prep P1: count_deg (vec4) || convert_w (tiled transpose) ----------------
// blocks [0, CB): degree count, 4 edges/thread.
// blocks [CB, CB + L*64): W transpose tiles 64x64: Wt[l][n][k] = bf16(W[l][k][n]).

__global__ __launch_bounds__(256) void prep1_kernel(const int* __restrict__ dst, int E, int CB,
                                                    int* __restrict__ cnt,
                                                    const float* __restrict__ W,
                                                    u16* __restrict__ Wt){
  if ((int)blockIdx.x < CB){
    int i4 = (blockIdx.x * 256 + threadIdx.x) * 4;
    if (i4 + 3 < E){
      i32x4 d = *(const i32x4*)(dst + i4);
      atomicAdd(&cnt[d[0]], 1); atomicAdd(&cnt[d[1]], 1);
      atomicAdd(&cnt[d[2]], 1); atomicAdd(&cnt[d[3]], 1);
    } else {
      for (int i = i4; i < E; ++i) atomicAdd(&cnt[dst[i]], 1);
    }
    return;
  }
  // ---- W transpose tile ----
  __shared__ u16 tile[64][72];
  const int tix = blockIdx.x - CB;        // 0 .. L*64-1
  const int l   = tix >> 6;
  const int kt  = ((tix >> 3) & 7) << 6;  // k tile base
  const int nt  = (tix & 7) << 6;         // n tile base
  const int tid = threadIdx.x;
  const int ty  = tid >> 4;               // 0..15
  const int tx  = tid & 15;               // 0..15 (4 floats each)
  const float* Wl = W + ((size_t)l << 18);
  #pragma unroll
  for (int q = 0; q < 4; ++q){
    const int row = (q << 4) + ty;        // k within tile
    f32x4 v = *(const f32x4*)(Wl + (((size_t)(kt + row)) << 9) + nt + (tx << 2));
    #pragma unroll
    for (int j = 0; j < 4; ++j) tile[(tx << 2) + j][row] = f2bf(v[j]);
  }
  __syncthreads();
  u16* Wtl = Wt + ((size_t)l << 18);
  #pragma unroll
  for (int rep = 0; rep < 2; ++rep){
    const int idx  = (rep << 8) + tid;    // 0..511
    const int nrow = idx >> 3;            // 0..63
    const int ch   = idx & 7;             // 8-u16 chunk
    u16x8 o;
    #pragma unroll
    for (int j = 0; j < 8; ++j) o[j] = tile[nrow][(ch << 3) + j];
    *(u16x8*)(Wtl + (((size_t)(nt + nrow)) << 9) + kt + (ch << 3)) = o;
  }
}

// ---------------- scan chain (unchanged) ----------------

__global__ void scan1_kernel(const int* __restrict__ cnt, int n,
                             int* __restrict__ excl, int* __restrict__ bsums){
  __shared__ int sd[1024];
  const int tid = threadIdx.x;
  const int i = blockIdx.x * 1024 + tid;
  int v = 0;
  if (i < n){ v = (cnt[i] + 7) & ~7; if (v == 0) v = 8; }  // every list >= 1 chunk
  sd[tid] = v;
  __syncthreads();
  for (int s = 1; s < 1024; s <<= 1){
    int t = (tid >= s) ? sd[tid - s] : 0;
    __syncthreads();
    sd[tid] += t;
    __syncthreads();
  }
  if (i < n) excl[i] = sd[tid] - v;
  if (tid == 1023) bsums[blockIdx.x] = sd[tid];
}

__global__ void scan2_kernel(int* __restrict__ bsums, int nb){
  __shared__ int sd[256];
  const int tid = threadIdx.x;
  int v = (tid < nb) ? bsums[tid] : 0;
  sd[tid] = v;
  __syncthreads();
  for (int s = 1; s < 256; s <<= 1){
    int t = (tid >= s) ? sd[tid - s] : 0;
    __syncthreads();
    sd[tid] += t;
    __syncthreads();
  }
  if (tid < nb) bsums[tid] = sd[tid] - v;
  if (tid == nb - 1) bsums[nb] = sd[tid];
}

__global__ void finalize_kernel(int* __restrict__ rowptr, int* __restrict__ cursor,
                                const int* __restrict__ bsums, int nb,
                                const int* __restrict__ cnt,
                                float* __restrict__ dis, int n){
  int i = blockIdx.x * blockDim.x + threadIdx.x;
  if (i < n){
    int r = rowptr[i] + bsums[i >> 10];
    rowptr[i] = r;
    cursor[i] = r;
    dis[i] = rsqrtf((float)(cnt[i] + 1)); // +1 self loop
  }
  if (i == 0){
    rowptr[n] = bsums[nb];
    dis[n] = 0.f;                          // sentinel node
  }
}

// ---------------- fused prep P3: convert_x || fill_csr || pad_fill ----------------
// blocks [0, XB): xs[row] = bf16(dis[row]*x[row]), pad rows zero.
// blocks [XB, XB+FB): CSR fill. blocks [XB+FB, XB+FB+PB): sentinel padding.

__global__ __launch_bounds__(256) void prep3_kernel(const float* __restrict__ x,
                                                    const float* __restrict__ dis,
                                                    u32* __restrict__ xb,
                                                    int n_real, int n_tot, int XB,
                                                    const int* __restrict__ src,
                                                    const int* __restrict__ dst,
                                                    int E, int FB,
                                                    int* __restrict__ cursor,
                                                    const int* __restrict__ rowptr,
                                                    const int* __restrict__ cnt,
                                                    int N,
                                                    u16* __restrict__ col){
  const int b = blockIdx.x;
  if (b < XB){
    int i8 = (b * 256 + threadIdx.x) * 8;
    if (i8 >= n_tot) return;
    u32 q0, q1, q2, q3;
    if (i8 < n_real){
      const float dv = dis[i8 >> 9];
      const f32x4* xp = (const f32x4*)(x + i8);
      f32x4 a = xp[0], v = xp[1];
      q0 = ((u32)f2bf(dv * a[1]) << 16) | f2bf(dv * a[0]);
      q1 = ((u32)f2bf(dv * a[3]) << 16) | f2bf(dv * a[2]);
      q2 = ((u32)f2bf(dv * v[1]) << 16) | f2bf(dv * v[0]);
      q3 = ((u32)f2bf(dv * v[3]) << 16) | f2bf(dv * v[2]);
    } else {
      q0 = q1 = q2 = q3 = 0u;  // pad rows (incl. sentinel N) stay zero
    }
    u32x4 q = {q0, q1, q2, q3};
    *(u32x4*)(xb + (i8 >> 1)) = q;
  } else if (b < XB + FB){
    int i = (b - XB) * 256 + threadIdx.x;
    if (i < E){
      int d = dst[i];
      int p = atomicAdd(&cursor[d], 1);
      col[p] = (u16)src[i];
    }
  } else {
    int v = (b - XB - FB) * 256 + threadIdx.x;
    if (v < N){
      int p = rowptr[v] + cnt[v];
      const int p1 = rowptr[v + 1];
      for (; p < p1; ++p) col[p] = (u16)N;   // disjoint from fill range
    }
    if (v == 0){
      int t = rowptr[N];
      for (int j = 0; j < 32; ++j) col[t + j] = (u16)N;
    }
  }
}

// ---------------- aggregation: one wave per node, 8-wide chunks, col 2-ahead ----------------
// agg[v] = dis[v] * ( xs[v] + sum_s xs[s] )   (xs bf16, f32 accum)
// lists padded to multiples of 8 (>=8) with sentinel N (xs[N]=0).

#define GATHER8(p, c) \
  p##0 = ld((u32)(c)[0]); p##1 = ld((u32)(c)[1]); p##2 = ld((u32)(c)[2]); p##3 = ld((u32)(c)[3]); \
  p##4 = ld((u32)(c)[4]); p##5 = ld((u32)(c)[5]); p##6 = ld((u32)(c)[6]); p##7 = ld((u32)(c)[7]);

#define ACCQ(q) \
  a0 += bflo((q)[0]); a1 += bfhi((q)[0]); a2 += bflo((q)[1]); a3 += bfhi((q)[1]); \
  a4 += bflo((q)[2]); a5 += bfhi((q)[2]); a6 += bflo((q)[3]); a7 += bfhi((q)[3]);

#define CONS8(p) \
  ACCQ(p##0) ACCQ(p##1) ACCQ(p##2) ACCQ(p##3) ACCQ(p##4) ACCQ(p##5) ACCQ(p##6) ACCQ(p##7)

__global__ __launch_bounds__(256) void aggregate_kernel(const char* __restrict__ xsb,
                                                        const int* __restrict__ rowptr,
                                                        const u16* __restrict__ col,
                                                        const float* __restrict__ dis,
                                                        u32* __restrict__ ob, int N){
  const int lane = threadIdx.x & 63;
  const int v = blockIdx.x * 4 + (threadIdx.x >> 6);
  if (v >= N) return;
  const u32 loff = (u32)(lane << 4);

  auto ld = [&](u32 node) -> u32x4 {
    return *(const u32x4*)(xsb + (((size_t)node << 10) + loff));
  };

  float a0, a1, a2, a3, a4, a5, a6, a7;
  {
    u32x4 q = ld((u32)v);  // self loop term
    a0 = bflo(q[0]); a1 = bfhi(q[0]); a2 = bflo(q[1]); a3 = bfhi(q[1]);
    a4 = bflo(q[2]); a5 = bfhi(q[2]); a6 = bflo(q[3]); a7 = bfhi(q[3]);
  }

  const int e0 = rowptr[v];
  const int m  = (rowptr[v + 1] - e0) >> 3;   // >= 1
  const u16* cp = col + e0;

  u32x4 qa0, qa1, qa2, qa3, qa4, qa5, qa6, qa7;
  u32x4 qb0, qb1, qb2, qb3, qb4, qb5, qb6, qb7;

  u16x8 c0 = *(const u16x8*)cp;
  u16x8 c1 = *(const u16x8*)(cp + 8);     // over-read -> sentinel slack
  GATHER8(qa, c0);

  int i = 1;
  for (; i + 1 < m; i += 2){
    c0 = *(const u16x8*)(cp + 8 * (i + 1));
    GATHER8(qb, c1);
    CONS8(qa);
    c1 = *(const u16x8*)(cp + 8 * (i + 2));
    GATHER8(qa, c0);
    CONS8(qb);
  }
  if (i < m){
    GATHER8(qb, c1);
    CONS8(qa);
    CONS8(qb);
  } else {
    CONS8(qa);
  }

  const float dv = dis[v];
  u32x4 r;
  r[0] = ((u32)f2bf(dv * a1) << 16) | f2bf(dv * a0);
  r[1] = ((u32)f2bf(dv * a3) << 16) | f2bf(dv * a2);
  r[2] = ((u32)f2bf(dv * a5) << 16) | f2bf(dv * a4);
  r[3] = ((u32)f2bf(dv * a7) << 16) | f2bf(dv * a6);
  *(u32x4*)(ob + (((size_t)v) << 8) + (lane << 2)) = r;
}

// ---------------- GEMM: 256x256 tile, BK=64, 512 thr (8 waves 2Mx4N), counted-vmcnt pipeline ----
// T3+T4 counted vmcnt(8) across raw barriers; T2 both-sides swizzle (rule #21); T5 setprio.

__global__ __launch_bounds__(512) void gemm_kernel(const u16* __restrict__ A,
                                                   const u16* __restrict__ Bt,
                                                   const float* __restrict__ bias,
                                                   const float* __restrict__ dis,
                                                   u16* __restrict__ Cb,
                                                   float* __restrict__ Cf,
                                                   int n_real, int last){
  extern __shared__ u16 smem[];
  u16* const sAb = smem;            // [2][256*64]
  u16* const sBb = smem + 32768;    // [2][256*64]

  // bijective XCD-chunk swizzle (nwg divisible by 8: 392 = 8*49)
  const int cpx = gridDim.x >> 3;
  const int wg  = (blockIdx.x & 7) * cpx + (blockIdx.x >> 3);
  const int bm0 = (wg >> 1) << 8;
  const int bn0 = (wg & 1) << 8;

  const int tid  = threadIdx.x;
  const int lane = tid & 63;
  const int wv   = tid >> 6;        // 0..7
  const int wm   = wv >> 2;         // 0..1 -> 128-row half
  const int wn   = wv & 3;          // 0..3 -> 64-col quarter
  const int lr   = lane & 15, lg = lane >> 4;

  const int r0 = tid >> 3;                      // stage row within 64-row pass
  const int cl = (tid & 7) << 3;                // linear LDS elem offset
  const int cg = ((tid & 7) ^ (r0 & 7)) << 3;   // pre-swizzled global elem offset

  f32x4 acc[8][4] = {};

  auto stage = [&](int bsel, int t){
    const int k0 = t << 6;
    u16* dA = sAb + (bsel << 14);
    u16* dB = sBb + (bsel << 14);
    #pragma unroll
    for (int p = 0; p < 4; ++p){
      const int row = (p << 6) + r0;
      gload_lds16(A  + (((size_t)(bm0 + row)) << 9) + k0 + cg, (void*)&dA[(row << 6) + cl]);
      gload_lds16(Bt + (((size_t)(bn0 + row)) << 9) + k0 + cg, (void*)&dB[(row << 6) + cl]);
    }
  };

  stage(0, 0);   // 8 loads/thread per stage
  stage(1, 1);   // 16 outstanding after prologue

  #pragma unroll
  for (int t = 0; t < 8; ++t){
    const int cur = t & 1;
    // wait tile t landed; tile t+1's 8 loads remain in flight (counted, never 0 mid-loop)
    if (t < 7) asm volatile("s_waitcnt vmcnt(8)" ::: "memory");
    else       asm volatile("s_waitcnt vmcnt(0)" ::: "memory");
    __builtin_amdgcn_s_barrier();
    __builtin_amdgcn_sched_barrier(0);

    const bf16x8* A8 = (const bf16x8*)(sAb + (cur << 14));
    const bf16x8* B8 = (const bf16x8*)(sBb + (cur << 14));
    __builtin_amdgcn_s_setprio(1);
    #pragma unroll
    for (int ks = 0; ks < 2; ++ks){
      const int cswz = ((ks << 2) + lg) ^ (lr & 7);   // read-side swizzled 16B chunk
      bf16x8 bg[4];
      #pragma unroll
      for (int ni = 0; ni < 4; ++ni)
        bg[ni] = B8[(((wn << 6) + (ni << 4) + lr) << 3) + cswz];
      #pragma unroll
      for (int mi = 0; mi < 8; ++mi){
        bf16x8 af = A8[(((wm << 7) + (mi << 4) + lr) << 3) + cswz];
        #pragma unroll
        for (int ni = 0; ni < 4; ++ni)
          acc[mi][ni] = __builtin_amdgcn_mfma_f32_16x16x32_bf16(af, bg[ni], acc[mi][ni], 0, 0, 0);
      }
    }
    __builtin_amdgcn_s_setprio(0);
    __builtin_amdgcn_sched_barrier(0);
    __builtin_amdgcn_s_barrier();      // all waves done reading buf[cur]
    if (t < 6) stage(cur, t + 2);      // refill freed buffer; overlaps next iter's MFMAs
  }

  float bb[4];
  #pragma unroll
  for (int ni = 0; ni < 4; ++ni) bb[ni] = bias[bn0 + (wn << 6) + (ni << 4) + lr];

  // C/D layout: col=lane&15, row=(lane>>4)*4+reg  [m89-verified]
  #pragma unroll
  for (int mi = 0; mi < 8; ++mi){
    const int row0 = bm0 + (wm << 7) + (mi << 4) + (lg << 2);
    const f32x4 dv4 = *(const f32x4*)(dis + row0);   // dis padded; rows>=n_real unused
    #pragma unroll
    for (int ni = 0; ni < 4; ++ni){
      const int c0 = bn0 + (wn << 6) + (ni << 4) + lr;
      #pragma unroll
      for (int r = 0; r < 4; ++r){
        const int row = row0 + r;
        const float val = fmaxf(acc[mi][ni][r] + bb[ni], 0.f);
        if (!last){
          Cb[(((size_t)row) << 9) + c0] = (row < n_real) ? f2bf(dv4[r] * val) : (u16)0;
        } else if (row < n_real){
          Cf[(((size_t)row) << 9) + c0] = val;
        }
      }
    }
  }
}

// ---------------- launch ----------------

extern "C" void kernel_launch(void* const* d_in, const int* in_sizes, int n_in,
                              void* d_out, int out_size, void* d_ws, size_t ws_size,
                              hipStream_t stream) {
  const float* x    = (const float*)d_in[0];
  const int*   ei   = (const int*)d_in[1];   // [2][E] int32: src = ei, dst = ei + E
  const float* W    = (const float*)d_in[2]; // [L][512][512]
  const float* bias = (const float*)d_in[3]; // [L][512]
  float* out = (float*)d_out;

  const int N = in_sizes[0] >> 9;       // 50000
  const int E = in_sizes[1] >> 1;       // 800000
  const int L = in_sizes[3] >> 9;       // 3
  const int MPAD = (N + 255) & ~255;    // 50176 (256-tile bands; > N so row N is a zero pad row)
  const int NB = (N + 1023) / 1024;     // scan blocks (49)

  char* p = (char*)d_ws;
  auto alloc = [&](size_t bytes){ char* q = p; p += (bytes + 255) & ~(size_t)255; return q; };
  u16*   xb       = (u16*)alloc((size_t)MPAD * 512 * 2);
  u16*   aggb     = (u16*)alloc((size_t)MPAD * 512 * 2);
  u16*   wt       = (u16*)alloc((size_t)L * 512 * 512 * 2);
  float* dis      = (float*)alloc((size_t)(MPAD + 4) * 4);  // padded for epilogue f32x4 reads
  int*   rowptr_d = (int*)alloc((size_t)(N + 1) * 4);
  int*   cursor_d = (int*)alloc((size_t)N * 4);
  int*   cnt_d    = (int*)alloc((size_t)N * 4);
  u16*   col      = (u16*)alloc(((size_t)E + 8 * (size_t)N + 64) * 2);
  int*   bsums_d  = (int*)alloc(256 * 4);

  hipFuncSetAttribute((const void*)gemm_kernel,
                      hipFuncAttributeMaxDynamicSharedMemorySize, 131072);

  hipMemsetAsync(cnt_d, 0, (size_t)N * 4, stream);
  // zero pad rows of aggb once per call; agg only writes rows < N
  hipMemsetAsync(aggb + (size_t)N * 512, 0, (size_t)(MPAD - N) * 512 * 2, stream);

  // P1: count_deg (vec4) || convert_w (transpose tiles)
  const int CB = (E / 4 + 255) / 256;     // 782
  prep1_kernel<<<CB + L * 64, 256, 0, stream>>>(ei + E, E, CB, cnt_d, W, wt);

  scan1_kernel<<<NB, 1024, 0, stream>>>(cnt_d, N, rowptr_d, bsums_d);
  scan2_kernel<<<1, 256, 0, stream>>>(bsums_d, NB);
  finalize_kernel<<<(N + 255) / 256, 256, 0, stream>>>(rowptr_d, cursor_d, bsums_d, NB, cnt_d, dis, N);

  // P3: convert_x || fill_csr || pad_fill
  const int ntot = MPAD * 512;
  const int XB = (ntot / 8 + 255) / 256;  // 12544
  const int FB = (E + 255) / 256;         // 3125
  const int PB = (N + 255) / 256;         // 196
  prep3_kernel<<<XB + FB + PB, 256, 0, stream>>>(x, dis, (u32*)xb, N * 512, ntot, XB,
                                                 ei, ei + E, E, FB,
                                                 cursor_d, rowptr_d, cnt_d, N, col);

  const int ggrid = (MPAD / 256) * 2;   // 392 = 8*49, divisible by 8
  for (int l = 0; l < L; ++l){
    aggregate_kernel<<<(N + 3) / 4, 256, 0, stream>>>((const char*)xb, rowptr_d, col, dis,
                                                      (u32*)aggb, N);
    gemm_kernel<<<ggrid, 512, 131072, stream>>>(aggb, wt + (size_t)l * 512 * 512,
                                                bias + (size_t)l * 512, dis,
                                                xb, out, N, (l == L - 1) ? 1 : 0);
  }
}

// Round 12
// 664.630 us; speedup vs baseline: 1.0107x; 1.0107x over previous
//
#include <hip/hip_runtime.h>
#include <hip/hip_bf16.h>

using u16 = unsigned short;
using u32 = unsigned int;

typedef __bf16 bf16x8 __attribute__((ext_vector_type(8)));
typedef float  f32x4  __attribute__((ext_vector_type(4)));
typedef u32    u32x4  __attribute__((ext_vector_type(4)));
typedef u16    u16x8  __attribute__((ext_vector_type(8)));
typedef int    i32x4  __attribute__((ext_vector_type(4)));

__device__ __forceinline__ float bflo(u32 u){ union { u32 u; float f; } c; c.u = u << 16;          return c.f; }
__device__ __forceinline__ float bfhi(u32 u){ union { u32 u; float f; } c; c.u = u & 0xffff0000u;  return c.f; }
__device__ __forceinline__ u16  f2bf(float f){
  union { float f; u32 u; } c; c.f = f;
  u32 u = c.u;
  return (u16)((u + 0x7fffu + ((u >> 16) & 1u)) >> 16); // RNE
}

__device__ __forceinline__ void gload_lds16(const void* g, void* l){
  __builtin_amdgcn_global_load_lds(
      (const __attribute__((address_space(1))) void*)g,
      (__attribute__((address_space(3))) void*)l, 16, 0, 0);
}

// ---------------- fused prep P1: count_deg (vec4) || convert_w (tiled transpose) ----------------

__global__ __launch_bounds__(256) void prep1_kernel(const int* __restrict__ dst, int E, int CB,
                                                    int* __restrict__ cnt,
                                                    const float* __restrict__ W,
                                                    u16* __restrict__ Wt){
  if ((int)blockIdx.x < CB){
    int i4 = (blockIdx.x * 256 + threadIdx.x) * 4;
    if (i4 + 3 < E){
      i32x4 d = *(const i32x4*)(dst + i4);
      atomicAdd(&cnt[d[0]], 1); atomicAdd(&cnt[d[1]], 1);
      atomicAdd(&cnt[d[2]], 1); atomicAdd(&cnt[d[3]], 1);
    } else {
      for (int i = i4; i < E; ++i) atomicAdd(&cnt[dst[i]], 1);
    }
    return;
  }
  // ---- W transpose tile: Wt[l][n][k] = bf16(W[l][k][n]) ----
  __shared__ u16 tile[64][72];
  const int tix = blockIdx.x - CB;        // 0 .. L*64-1
  const int l   = tix >> 6;
  const int kt  = ((tix >> 3) & 7) << 6;  // k tile base
  const int nt  = (tix & 7) << 6;         // n tile base
  const int tid = threadIdx.x;
  const int ty  = tid >> 4;               // 0..15
  const int tx  = tid & 15;               // 0..15 (4 floats each)
  const float* Wl = W + ((size_t)l << 18);
  #pragma unroll
  for (int q = 0; q < 4; ++q){
    const int row = (q << 4) + ty;        // k within tile
    f32x4 v = *(const f32x4*)(Wl + (((size_t)(kt + row)) << 9) + nt + (tx << 2));
    #pragma unroll
    for (int j = 0; j < 4; ++j) tile[(tx << 2) + j][row] = f2bf(v[j]);
  }
  __syncthreads();
  u16* Wtl = Wt + ((size_t)l << 18);
  #pragma unroll
  for (int rep = 0; rep < 2; ++rep){
    const int idx  = (rep << 8) + tid;    // 0..511
    const int nrow = idx >> 3;            // 0..63
    const int ch   = idx & 7;             // 8-u16 chunk
    u16x8 o;
    #pragma unroll
    for (int j = 0; j < 8; ++j) o[j] = tile[nrow][(ch << 3) + j];
    *(u16x8*)(Wtl + (((size_t)(nt + nrow)) << 9) + kt + (ch << 3)) = o;
  }
}

// ---------------- scan chain ----------------

__global__ void scan1_kernel(const int* __restrict__ cnt, int n,
                             int* __restrict__ excl, int* __restrict__ bsums){
  __shared__ int sd[1024];
  const int tid = threadIdx.x;
  const int i = blockIdx.x * 1024 + tid;
  int v = 0;
  if (i < n){ v = (cnt[i] + 7) & ~7; if (v == 0) v = 8; }  // every list >= 1 chunk
  sd[tid] = v;
  __syncthreads();
  for (int s = 1; s < 1024; s <<= 1){
    int t = (tid >= s) ? sd[tid - s] : 0;
    __syncthreads();
    sd[tid] += t;
    __syncthreads();
  }
  if (i < n) excl[i] = sd[tid] - v;
  if (tid == 1023) bsums[blockIdx.x] = sd[tid];
}

__global__ void scan2_kernel(int* __restrict__ bsums, int nb){
  __shared__ int sd[256];
  const int tid = threadIdx.x;
  int v = (tid < nb) ? bsums[tid] : 0;
  sd[tid] = v;
  __syncthreads();
  for (int s = 1; s < 256; s <<= 1){
    int t = (tid >= s) ? sd[tid - s] : 0;
    __syncthreads();
    sd[tid] += t;
    __syncthreads();
  }
  if (tid < nb) bsums[tid] = sd[tid] - v;
  if (tid == nb - 1) bsums[nb] = sd[tid];
}

__global__ void finalize_kernel(int* __restrict__ rowptr, int* __restrict__ cursor,
                                const int* __restrict__ bsums, int nb,
                                const int* __restrict__ cnt,
                                float* __restrict__ dis, int n){
  int i = blockIdx.x * blockDim.x + threadIdx.x;
  if (i < n){
    int r = rowptr[i] + bsums[i >> 10];
    rowptr[i] = r;
    cursor[i] = r;
    dis[i] = rsqrtf((float)(cnt[i] + 1)); // +1 self loop
  }
  if (i == 0){
    rowptr[n] = bsums[nb];
    dis[n] = 0.f;                          // sentinel node
  }
}

// ---------------- fused prep P3: convert_x || fill_csr || pad_fill ----------------

__global__ __launch_bounds__(256) void prep3_kernel(const float* __restrict__ x,
                                                    const float* __restrict__ dis,
                                                    u32* __restrict__ xb,
                                                    int n_real, int n_tot, int XB,
                                                    const int* __restrict__ src,
                                                    const int* __restrict__ dst,
                                                    int E, int FB,
                                                    int* __restrict__ cursor,
                                                    const int* __restrict__ rowptr,
                                                    const int* __restrict__ cnt,
                                                    int N,
                                                    u16* __restrict__ col){
  const int b = blockIdx.x;
  if (b < XB){
    int i8 = (b * 256 + threadIdx.x) * 8;
    if (i8 >= n_tot) return;
    u32 q0, q1, q2, q3;
    if (i8 < n_real){
      const float dv = dis[i8 >> 9];
      const f32x4* xp = (const f32x4*)(x + i8);
      f32x4 a = xp[0], v = xp[1];
      q0 = ((u32)f2bf(dv * a[1]) << 16) | f2bf(dv * a[0]);
      q1 = ((u32)f2bf(dv * a[3]) << 16) | f2bf(dv * a[2]);
      q2 = ((u32)f2bf(dv * v[1]) << 16) | f2bf(dv * v[0]);
      q3 = ((u32)f2bf(dv * v[3]) << 16) | f2bf(dv * v[2]);
    } else {
      q0 = q1 = q2 = q3 = 0u;  // pad rows (incl. sentinel N) stay zero
    }
    u32x4 q = {q0, q1, q2, q3};
    *(u32x4*)(xb + (i8 >> 1)) = q;
  } else if (b < XB + FB){
    int i = (b - XB) * 256 + threadIdx.x;
    if (i < E){
      int d = dst[i];
      int p = atomicAdd(&cursor[d], 1);
      col[p] = (u16)src[i];
    }
  } else {
    int v = (b - XB - FB) * 256 + threadIdx.x;
    if (v < N){
      int p = rowptr[v] + cnt[v];
      const int p1 = rowptr[v + 1];
      for (; p < p1; ++p) col[p] = (u16)N;
    }
    if (v == 0){
      int t = rowptr[N];
      for (int j = 0; j < 32; ++j) col[t + j] = (u16)N;
    }
  }
}

// ---------------- aggregation: one wave per node, 8-wide chunks, col 2-ahead ----------------

#define GATHER8(p, c) \
  p##0 = ld((u32)(c)[0]); p##1 = ld((u32)(c)[1]); p##2 = ld((u32)(c)[2]); p##3 = ld((u32)(c)[3]); \
  p##4 = ld((u32)(c)[4]); p##5 = ld((u32)(c)[5]); p##6 = ld((u32)(c)[6]); p##7 = ld((u32)(c)[7]);

#define ACCQ(q) \
  a0 += bflo((q)[0]); a1 += bfhi((q)[0]); a2 += bflo((q)[1]); a3 += bfhi((q)[1]); \
  a4 += bflo((q)[2]); a5 += bfhi((q)[2]); a6 += bflo((q)[3]); a7 += bfhi((q)[3]);

#define CONS8(p) \
  ACCQ(p##0) ACCQ(p##1) ACCQ(p##2) ACCQ(p##3) ACCQ(p##4) ACCQ(p##5) ACCQ(p##6) ACCQ(p##7)

__global__ __launch_bounds__(256) void aggregate_kernel(const char* __restrict__ xsb,
                                                        const int* __restrict__ rowptr,
                                                        const u16* __restrict__ col,
                                                        const float* __restrict__ dis,
                                                        u32* __restrict__ ob, int N){
  const int lane = threadIdx.x & 63;
  const int v = blockIdx.x * 4 + (threadIdx.x >> 6);
  if (v >= N) return;
  const u32 loff = (u32)(lane << 4);

  auto ld = [&](u32 node) -> u32x4 {
    return *(const u32x4*)(xsb + (((size_t)node << 10) + loff));
  };

  float a0, a1, a2, a3, a4, a5, a6, a7;
  {
    u32x4 q = ld((u32)v);  // self loop term
    a0 = bflo(q[0]); a1 = bfhi(q[0]); a2 = bflo(q[1]); a3 = bfhi(q[1]);
    a4 = bflo(q[2]); a5 = bfhi(q[2]); a6 = bflo(q[3]); a7 = bfhi(q[3]);
  }

  const int e0 = rowptr[v];
  const int m  = (rowptr[v + 1] - e0) >> 3;   // >= 1
  const u16* cp = col + e0;

  u32x4 qa0, qa1, qa2, qa3, qa4, qa5, qa6, qa7;
  u32x4 qb0, qb1, qb2, qb3, qb4, qb5, qb6, qb7;

  u16x8 c0 = *(const u16x8*)cp;
  u16x8 c1 = *(const u16x8*)(cp + 8);     // over-read -> sentinel slack
  GATHER8(qa, c0);

  int i = 1;
  for (; i + 1 < m; i += 2){
    c0 = *(const u16x8*)(cp + 8 * (i + 1));
    GATHER8(qb, c1);
    CONS8(qa);
    c1 = *(const u16x8*)(cp + 8 * (i + 2));
    GATHER8(qa, c0);
    CONS8(qb);
  }
  if (i < m){
    GATHER8(qb, c1);
    CONS8(qa);
    CONS8(qb);
  } else {
    CONS8(qa);
  }

  const float dv = dis[v];
  u32x4 r;
  r[0] = ((u32)f2bf(dv * a1) << 16) | f2bf(dv * a0);
  r[1] = ((u32)f2bf(dv * a3) << 16) | f2bf(dv * a2);
  r[2] = ((u32)f2bf(dv * a5) << 16) | f2bf(dv * a4);
  r[3] = ((u32)f2bf(dv * a7) << 16) | f2bf(dv * a6);
  *(u32x4*)(ob + (((size_t)v) << 8) + (lane << 2)) = r;
}

// ---------------- GEMM: BM=128 x BN=512(full) x BK=32, 512 thr (8 waves 2Mx4N) ----------------
// A row-band staged ONCE per GEMM (min L3 traffic); B (512KB) re-read from local L2 (cheap).
// LDS 80 KB/block (A 2x8KB + B 2x32KB dbuf) -> 2 blocks/CU (160KB exact) for cross-block overlap.
// T3+T4 counted vmcnt(5); T2 both-sides chunk swizzle c^((row>>1)&3) (rule #21); T5 setprio.

__global__ __launch_bounds__(512) void gemm_kernel(const u16* __restrict__ A,
                                                   const u16* __restrict__ Bt,
                                                   const float* __restrict__ bias,
                                                   const float* __restrict__ dis,
                                                   u16* __restrict__ Cb,
                                                   float* __restrict__ Cf,
                                                   int n_real, int last){
  extern __shared__ u16 smem[];
  u16* const sAb = smem;            // [2][128*32] u16
  u16* const sBb = smem + 8192;     // [2][512*32] u16

  // bijective XCD-chunk swizzle (nwg divisible by 8: 392 = 8*49)
  const int cpx = gridDim.x >> 3;
  const int wg  = (blockIdx.x & 7) * cpx + (blockIdx.x >> 3);
  const int bm0 = wg << 7;

  const int tid  = threadIdx.x;
  const int lane = tid & 63;
  const int wv   = tid >> 6;        // 0..7
  const int wm   = wv >> 2;         // 0..1 -> 64-row half
  const int wn   = wv & 3;          // 0..3 -> 128-col quarter
  const int lr   = lane & 15, lg = lane >> 4;

  f32x4 acc[4][8] = {};

  auto stage = [&](int bsel, int t){
    const int k0 = t << 5;
    u16* dA = sAb + (bsel << 12);
    u16* dB = sBb + (bsel << 14);
    {
      const int row = tid >> 2;
      const int gq  = ((tid & 3) ^ ((row >> 1) & 3)) << 3;   // pre-swizzled global chunk
      gload_lds16(A + (((size_t)(bm0 + row)) << 9) + k0 + gq,
                  (void*)&dA[(row << 5) + ((tid & 3) << 3)]); // linear dest (lane x 16B)
    }
    #pragma unroll
    for (int p = 0; p < 4; ++p){
      const int row = (tid >> 2) + (p << 7);
      const int gq  = ((tid & 3) ^ ((row >> 1) & 3)) << 3;
      gload_lds16(Bt + (((size_t)row) << 9) + k0 + gq,
                  (void*)&dB[(row << 5) + ((tid & 3) << 3)]);
    }
  };

  stage(0, 0);   // 5 loads/thread per stage
  stage(1, 1);   // 10 outstanding after prologue

  #pragma unroll
  for (int t = 0; t < 16; ++t){
    const int cur = t & 1;
    // wait tile t landed; tile t+1's 5 loads stay in flight (never drain to 0 mid-loop)
    if (t < 15) asm volatile("s_waitcnt vmcnt(5)" ::: "memory");
    else        asm volatile("s_waitcnt vmcnt(0)" ::: "memory");
    __builtin_amdgcn_s_barrier();
    __builtin_amdgcn_sched_barrier(0);

    const bf16x8* A8 = (const bf16x8*)(sAb + (cur << 12));
    const bf16x8* B8 = (const bf16x8*)(sBb + (cur << 14));
    __builtin_amdgcn_s_setprio(1);
    bf16x8 af[4], bg[8];
    #pragma unroll
    for (int mi = 0; mi < 4; ++mi){
      const int row = (wm << 6) + (mi << 4) + lr;
      af[mi] = A8[(row << 2) + (lg ^ ((row >> 1) & 3))];     // read-side swizzle
    }
    #pragma unroll
    for (int ni = 0; ni < 8; ++ni){
      const int row = (wn << 7) + (ni << 4) + lr;
      bg[ni] = B8[(row << 2) + (lg ^ ((row >> 1) & 3))];
    }
    #pragma unroll
    for (int mi = 0; mi < 4; ++mi)
      #pragma unroll
      for (int ni = 0; ni < 8; ++ni)
        acc[mi][ni] = __builtin_amdgcn_mfma_f32_16x16x32_bf16(af[mi], bg[ni], acc[mi][ni], 0, 0, 0);
    __builtin_amdgcn_s_setprio(0);
    __builtin_amdgcn_sched_barrier(0);
    __builtin_amdgcn_s_barrier();      // all waves done reading buf[cur]
    if (t < 14) stage(cur, t + 2);     // refill freed buffer
  }

  float bb[8];
  #pragma unroll
  for (int ni = 0; ni < 8; ++ni) bb[ni] = bias[(wn << 7) + (ni << 4) + lr];

  // C/D layout: col=lane&15, row=(lane>>4)*4+reg  [m89-verified]
  #pragma unroll
  for (int mi = 0; mi < 4; ++mi){
    const int row0 = bm0 + (wm << 6) + (mi << 4) + (lg << 2);
    const f32x4 dv4 = *(const f32x4*)(dis + row0);   // dis padded; rows>=n_real unused
    #pragma unroll
    for (int ni = 0; ni < 8; ++ni){
      const int c0 = (wn << 7) + (ni << 4) + lr;
      #pragma unroll
      for (int r = 0; r < 4; ++r){
        const int row = row0 + r;
        const float val = fmaxf(acc[mi][ni][r] + bb[ni], 0.f);
        if (!last){
          Cb[(((size_t)row) << 9) + c0] = (row < n_real) ? f2bf(dv4[r] * val) : (u16)0;
        } else if (row < n_real){
          Cf[(((size_t)row) << 9) + c0] = val;
        }
      }
    }
  }
}

// ---------------- launch ----------------

extern "C" void kernel_launch(void* const* d_in, const int* in_sizes, int n_in,
                              void* d_out, int out_size, void* d_ws, size_t ws_size,
                              hipStream_t stream) {
  const float* x    = (const float*)d_in[0];
  const int*   ei   = (const int*)d_in[1];   // [2][E] int32: src = ei, dst = ei + E
  const float* W    = (const float*)d_in[2]; // [L][512][512]
  const float* bias = (const float*)d_in[3]; // [L][512]
  float* out = (float*)d_out;

  const int N = in_sizes[0] >> 9;       // 50000
  const int E = in_sizes[1] >> 1;       // 800000
  const int L = in_sizes[3] >> 9;       // 3
  const int MPAD = (N + 255) & ~255;    // 50176 (> N so row N is a zero pad row; 392 = 8*49 bands)
  const int NB = (N + 1023) / 1024;     // scan blocks (49)

  char* p = (char*)d_ws;
  auto alloc = [&](size_t bytes){ char* q = p; p += (bytes + 255) & ~(size_t)255; return q; };
  u16*   xb       = (u16*)alloc((size_t)MPAD * 512 * 2);
  u16*   aggb     = (u16*)alloc((size_t)MPAD * 512 * 2);
  u16*   wt       = (u16*)alloc((size_t)L * 512 * 512 * 2);
  float* dis      = (float*)alloc((size_t)(MPAD + 4) * 4);  // padded for epilogue f32x4 reads
  int*   rowptr_d = (int*)alloc((size_t)(N + 1) * 4);
  int*   cursor_d = (int*)alloc((size_t)N * 4);
  int*   cnt_d    = (int*)alloc((size_t)N * 4);
  u16*   col      = (u16*)alloc(((size_t)E + 8 * (size_t)N + 64) * 2);
  int*   bsums_d  = (int*)alloc(256 * 4);

  hipFuncSetAttribute((const void*)gemm_kernel,
                      hipFuncAttributeMaxDynamicSharedMemorySize, 81920);

  hipMemsetAsync(cnt_d, 0, (size_t)N * 4, stream);
  // zero pad rows of aggb once per call; agg only writes rows < N
  hipMemsetAsync(aggb + (size_t)N * 512, 0, (size_t)(MPAD - N) * 512 * 2, stream);

  // P1: count_deg (vec4) || convert_w (transpose tiles)
  const int CB = (E / 4 + 255) / 256;     // 782
  prep1_kernel<<<CB + L * 64, 256, 0, stream>>>(ei + E, E, CB, cnt_d, W, wt);

  scan1_kernel<<<NB, 1024, 0, stream>>>(cnt_d, N, rowptr_d, bsums_d);
  scan2_kernel<<<1, 256, 0, stream>>>(bsums_d, NB);
  finalize_kernel<<<(N + 255) / 256, 256, 0, stream>>>(rowptr_d, cursor_d, bsums_d, NB, cnt_d, dis, N);

  // P3: convert_x || fill_csr || pad_fill
  const int ntot = MPAD * 512;
  const int XB = (ntot / 8 + 255) / 256;  // 12544
  const int FB = (E + 255) / 256;         // 3125
  const int PB = (N + 255) / 256;         // 196
  prep3_kernel<<<XB + FB + PB, 256, 0, stream>>>(x, dis, (u32*)xb, N * 512, ntot, XB,
                                                 ei, ei + E, E, FB,
                                                 cursor_d, rowptr_d, cnt_d, N, col);

  const int ggrid = MPAD / 128;         // 392 = 8*49, divisible by 8
  for (int l = 0; l < L; ++l){
    aggregate_kernel<<<(N + 3) / 4, 256, 0, stream>>>((const char*)xb, rowptr_d, col, dis,
                                                      (u32*)aggb, N);
    gemm_kernel<<<ggrid, 512, 81920, stream>>>(aggb, wt + (size_t)l * 512 * 512,
                                               bias + (size_t)l * 512, dis,
                                               xb, out, N, (l == L - 1) ? 1 : 0);
  }
}